// Round 6
// baseline (355.202 us; speedup 1.0000x reference)
//
#include <hip/hip_runtime.h>
#include <stdint.h>

#define NN 8192
#define FIN 128
#define FH 64
#define FO 16
#define BM 64
#define BN 64
#define SPLIT 8
#define NRANGE (NN / SPLIT)   // 1024
#define NCHUNK (NRANGE / BN)  // 16

typedef float    f32x4 __attribute__((ext_vector_type(4)));
typedef _Float16 f16x4 __attribute__((ext_vector_type(4)));

static __device__ __forceinline__ void fma4(float4& acc, float a, const float4 s) {
  acc.x = fmaf(a, s.x, acc.x);
  acc.y = fmaf(a, s.y, acc.y);
  acc.z = fmaf(a, s.z, acc.z);
  acc.w = fmaf(a, s.w, acc.w);
}

// ---------------- S1 = x @ W1  (8192x128 @ 128x64) ----------------
__global__ __launch_bounds__(256) void k_s1(const float* __restrict__ x,
                                            const float* __restrict__ W1,
                                            float* __restrict__ S1) {
  __shared__ float W1l[FIN * FH];
  __shared__ float xl[16][FIN + 4];
  const int t = threadIdx.x;
  const int n0 = blockIdx.x * 16;
  for (int i = t; i < FIN * FH / 4; i += 256)
    ((float4*)W1l)[i] = ((const float4*)W1)[i];
  for (int i = t; i < 16 * FIN; i += 256) {
    int r = i >> 7, c = i & (FIN - 1);
    xl[r][c] = x[(size_t)(n0 + r) * FIN + c];
  }
  __syncthreads();
  const int m = t >> 4;
  const int j0 = (t & 15) << 2;
  float4 acc = {0.f, 0.f, 0.f, 0.f};
#pragma unroll 8
  for (int k = 0; k < FIN; ++k) {
    float xv = xl[m][k];
    float4 w = *(const float4*)&W1l[k * FH + j0];
    fma4(acc, xv, w);
  }
  *(float4*)&S1[(size_t)(n0 + m) * FH + j0] = acc;
}

// ===== pass 1 (FUSED): hpart[sp] = (softmax(pi1)·adj)@S1 ; also emit A2h = fp16(pi2·adj) =====
__global__ __launch_bounds__(256, 4) void k_pass1_fused(const float* __restrict__ adj,
                                                        const float* __restrict__ S1,
                                                        const float* __restrict__ pi1,
                                                        const float* __restrict__ pi2,
                                                        float* __restrict__ hpart,
                                                        _Float16* __restrict__ A2h) {
  __shared__ float Alds[BN][BM];   // [n][m ^ (n&60)]  16 KB
  __shared__ float S1l[BN][FH];    // 16 KB
  const int t = threadIdx.x;
  const int mb = blockIdx.x >> 3;  // 0..127
  const int sp = blockIdx.x & 7;   // 0..7

  float p0 = pi1[0], p1 = pi1[1], p2 = pi1[2], p3 = pi1[3];
  float mx = fmaxf(fmaxf(p0, p1), fmaxf(p2, p3));
  float e0 = expf(p0 - mx), e1 = expf(p1 - mx), e2 = expf(p2 - mx), e3 = expf(p3 - mx);
  float inv = 1.0f / (e0 + e1 + e2 + e3);
  const float w0 = e0 * inv, w1 = e1 * inv, w2 = e2 * inv, w3 = e3 * inv;
  const float v0 = pi2[0], v1 = pi2[1], v2 = pi2[2], v3 = pi2[3];   // raw pi2

  const size_t NN2 = (size_t)NN * NN;
  const size_t row0 = (size_t)mb * BM;
  const int nbase = sp * NRANGE;

  const int n4 = t & 15;           // n-quad (staging)
  const int ms = t >> 4;           // row slot (staging), row = ms + 16*p
  const int m0 = (t & 15) << 2;    // compute 4x4 tile
  const int j0 = (t >> 4) << 2;

  f32x4 pf[4][4];
  f32x4 pfS[4];

  float4 acc0 = {0,0,0,0}, acc1 = {0,0,0,0}, acc2 = {0,0,0,0}, acc3 = {0,0,0,0};

  auto ISSUE = [&](int c) {
    const int n0 = nbase + c * BN;
#pragma unroll
    for (int p = 0; p < 4; ++p) {
      const float* g = adj + (row0 + (size_t)(ms + (p << 4))) * NN + (size_t)(n0 + (n4 << 2));
      pf[p][0] = __builtin_nontemporal_load((const f32x4*)g);
      pf[p][1] = __builtin_nontemporal_load((const f32x4*)(g + NN2));
      pf[p][2] = __builtin_nontemporal_load((const f32x4*)(g + 2 * NN2));
      pf[p][3] = __builtin_nontemporal_load((const f32x4*)(g + 3 * NN2));
    }
    const f32x4* src = (const f32x4*)(S1 + (size_t)n0 * FH);
#pragma unroll
    for (int i = 0; i < 4; ++i) pfS[i] = src[t + 256 * i];
  };

  auto STAGE = [&](int c) {
    const int n0 = nbase + c * BN;
#pragma unroll
    for (int p = 0; p < 4; ++p) {
      const int ml = ms + (p << 4);
      const int mc = ml ^ (n4 << 2);
      f32x4 a0 = pf[p][0], a1 = pf[p][1], a2 = pf[p][2], a3 = pf[p][3];
      // pi1 (softmaxed) combo -> LDS for this pass's GEMM
      Alds[(n4 << 2) + 0][mc] = fmaf(w0, a0.x, fmaf(w1, a1.x, fmaf(w2, a2.x, w3 * a3.x)));
      Alds[(n4 << 2) + 1][mc] = fmaf(w0, a0.y, fmaf(w1, a1.y, fmaf(w2, a2.y, w3 * a3.y)));
      Alds[(n4 << 2) + 2][mc] = fmaf(w0, a0.z, fmaf(w1, a1.z, fmaf(w2, a2.z, w3 * a3.z)));
      Alds[(n4 << 2) + 3][mc] = fmaf(w0, a0.w, fmaf(w1, a1.w, fmaf(w2, a2.w, w3 * a3.w)));
      // pi2 (raw) combo -> fp16 A2 tile for pass 2 (reuses the same adj registers)
      f16x4 h4;
      h4.x = (_Float16)fmaf(v0, a0.x, fmaf(v1, a1.x, fmaf(v2, a2.x, v3 * a3.x)));
      h4.y = (_Float16)fmaf(v0, a0.y, fmaf(v1, a1.y, fmaf(v2, a2.y, v3 * a3.y)));
      h4.z = (_Float16)fmaf(v0, a0.z, fmaf(v1, a1.z, fmaf(v2, a2.z, v3 * a3.z)));
      h4.w = (_Float16)fmaf(v0, a0.w, fmaf(v1, a1.w, fmaf(v2, a2.w, v3 * a3.w)));
      __builtin_nontemporal_store(h4, (f16x4*)(A2h + (row0 + (size_t)ml) * NN + (size_t)(n0 + (n4 << 2))));
    }
    f32x4* dst = (f32x4*)&S1l[0][0];
#pragma unroll
    for (int i = 0; i < 4; ++i) dst[t + 256 * i] = pfS[i];
  };

  ISSUE(0);
  for (int c = 0; c < NCHUNK; ++c) {
    __syncthreads();                 // drains vmcnt(0): prefetched loads completed during compute
    STAGE(c);
    if (c + 1 < NCHUNK) ISSUE(c + 1);
    asm volatile("s_waitcnt lgkmcnt(0)" ::: "memory");
    __builtin_amdgcn_s_barrier();
#pragma unroll 4
    for (int n = 0; n < BN; ++n) {
      const float4 a = *(const float4*)&Alds[n][m0 ^ (n & 60)];
      const float4 s = *(const float4*)&S1l[n][j0];
      fma4(acc0, a.x, s);
      fma4(acc1, a.y, s);
      fma4(acc2, a.z, s);
      fma4(acc3, a.w, s);
    }
  }
  float* hp = hpart + (size_t)sp * NN * FH;
  const size_t rbase = (row0 + m0) * FH + j0;
  *(float4*)&hp[rbase]          = acc0;
  *(float4*)&hp[rbase + FH]     = acc1;
  *(float4*)&hp[rbase + 2 * FH] = acc2;
  *(float4*)&hp[rbase + 3 * FH] = acc3;
}

// ---------------- exact JAX threefry2x32 dropout (partitionable path), key=(0,42) ----------
__device__ __forceinline__ float dropout_scale(uint32_t e) {
  uint32_t x0 = 0u;
  uint32_t x1 = e;
  const uint32_t ks1 = 42u;
  const uint32_t ks2 = 0x1BD11BF0u;
  x1 += ks1;
#define TFR(d) { x0 += x1; x1 = (x1 << d) | (x1 >> (32 - d)); x1 ^= x0; }
  TFR(13) TFR(15) TFR(26) TFR(6)   x0 += ks1; x1 += ks2 + 1u;
  TFR(17) TFR(29) TFR(16) TFR(24)  x0 += ks2; x1 += 0u  + 2u;
  TFR(13) TFR(15) TFR(26) TFR(6)   x0 += 0u;  x1 += ks1 + 3u;
  TFR(17) TFR(29) TFR(16) TFR(24)  x0 += ks1; x1 += ks2 + 4u;
  TFR(13) TFR(15) TFR(26) TFR(6)   x0 += ks2; x1 += 0u  + 5u;
#undef TFR
  uint32_t bits = x0 ^ x1;
  float u = __uint_as_float((bits >> 9) | 0x3f800000u) - 1.0f;
  return (u < 0.7f) ? (1.0f / 0.7f) : 0.0f;
}

// ---------------- mid: h = dropout(relu(sum_sp hpart + b1)); HW = h @ W2 ----------------
__global__ __launch_bounds__(256) void k_mid(const float* __restrict__ hpart,
                                             const float* __restrict__ b1,
                                             const float* __restrict__ W2,
                                             float* __restrict__ HW) {
  __shared__ float hl[4][FH];
  __shared__ float W2l[FH * FO];
  const int t = threadIdx.x;
  const int n0 = blockIdx.x << 2;
  for (int i = t; i < FH * FO; i += 256) W2l[i] = W2[i];
  const int j = t & 63, r = t >> 6;
  const uint32_t idx = (uint32_t)(n0 + r) * FH + j;
  const size_t NF = (size_t)NN * FH;
  float pre = b1[j];
#pragma unroll
  for (int s = 0; s < SPLIT; ++s) pre += hpart[idx + (size_t)s * NF];
  float v = fmaxf(pre, 0.0f) * dropout_scale(idx);
  hl[r][j] = v;
  __syncthreads();
  if (t < 64) {
    const int rr = t >> 4, f = t & 15;
    float s = 0.f;
#pragma unroll 8
    for (int jj = 0; jj < FH; ++jj)
      s = fmaf(hl[rr][jj], W2l[jj * FO + f], s);
    HW[(size_t)(n0 + rr) * FO + f] = s;
  }
}

// ===== pass 2: opart[sp] = A2h(fp16) @ HW — reads 128 MB instead of 1.07 GB =====
__global__ __launch_bounds__(256, 4) void k_pass2_half(const _Float16* __restrict__ A2h,
                                                       const float* __restrict__ HW,
                                                       float* __restrict__ opart) {
  __shared__ float Alds[BN][BM];   // 16 KB
  __shared__ float HWl[BN * FO];   // 4 KB
  const int t = threadIdx.x;
  const int mb = blockIdx.x >> 3;
  const int sp = blockIdx.x & 7;

  const size_t row0 = (size_t)mb * BM;
  const int nbase = sp * NRANGE;

  const int n4 = t & 15;
  const int ms = t >> 4;
  const int m0 = (t & 15) << 2;
  const int f  = t >> 4;

  f16x4 pf[4];
  f32x4 pfH;

  float4 acc = {0,0,0,0};

  auto ISSUE = [&](int c) {
    const int n0 = nbase + c * BN;
#pragma unroll
    for (int p = 0; p < 4; ++p)
      pf[p] = *(const f16x4*)(A2h + (row0 + (size_t)(ms + (p << 4))) * NN + (size_t)(n0 + (n4 << 2)));
    pfH = ((const f32x4*)(HW + (size_t)n0 * FO))[t];
  };

  auto STAGE = [&]() {
#pragma unroll
    for (int p = 0; p < 4; ++p) {
      const int mc = (ms + (p << 4)) ^ (n4 << 2);
      Alds[(n4 << 2) + 0][mc] = (float)pf[p].x;
      Alds[(n4 << 2) + 1][mc] = (float)pf[p].y;
      Alds[(n4 << 2) + 2][mc] = (float)pf[p].z;
      Alds[(n4 << 2) + 3][mc] = (float)pf[p].w;
    }
    ((f32x4*)HWl)[t] = pfH;
  };

  ISSUE(0);
  for (int c = 0; c < NCHUNK; ++c) {
    __syncthreads();
    STAGE();
    if (c + 1 < NCHUNK) ISSUE(c + 1);
    asm volatile("s_waitcnt lgkmcnt(0)" ::: "memory");
    __builtin_amdgcn_s_barrier();
#pragma unroll 4
    for (int n = 0; n < BN; ++n) {
      const float4 a = *(const float4*)&Alds[n][m0 ^ (n & 60)];
      const float hv = HWl[n * FO + f];
      acc.x = fmaf(a.x, hv, acc.x);
      acc.y = fmaf(a.y, hv, acc.y);
      acc.z = fmaf(a.z, hv, acc.z);
      acc.w = fmaf(a.w, hv, acc.w);
    }
  }
  float* op = opart + (size_t)sp * NN * FO;
  const size_t r = (row0 + m0) * FO + f;
  op[r]          = acc.x;
  op[r + FO]     = acc.y;
  op[r + 2 * FO] = acc.z;
  op[r + 3 * FO] = acc.w;
}

// ---------------- final: out = sum_sp opart + b2 ----------------
__global__ __launch_bounds__(256) void k_fin(const float* __restrict__ opart,
                                             const float* __restrict__ b2,
                                             float* __restrict__ out) {
  const int e = blockIdx.x * 256 + threadIdx.x;
  const size_t NFo = (size_t)NN * FO;
  float s = b2[e & 15];
#pragma unroll
  for (int p = 0; p < SPLIT; ++p) s += opart[e + (size_t)p * NFo];
  out[e] = s;
}

extern "C" void kernel_launch(void* const* d_in, const int* in_sizes, int n_in,
                              void* d_out, int out_size, void* d_ws, size_t ws_size,
                              hipStream_t stream) {
  const float* adj = (const float*)d_in[0];
  const float* x   = (const float*)d_in[1];
  const float* W1  = (const float*)d_in[2];
  const float* b1  = (const float*)d_in[3];
  const float* W2  = (const float*)d_in[4];
  const float* b2  = (const float*)d_in[5];
  const float* pi1 = (const float*)d_in[6];
  const float* pi2 = (const float*)d_in[7];
  float* out = (float*)d_out;
  float* ws  = (float*)d_ws;

  // ws layout (floats): S1[NN*FH] | hpart[SPLIT*NN*FH] | HW[NN*FO] | opart[SPLIT*NN*FO] | A2h(fp16 NN*NN)
  float* S1    = ws;
  float* hpart = S1 + (size_t)NN * FH;
  float* HW    = hpart + (size_t)SPLIT * NN * FH;
  float* opart = HW + (size_t)NN * FO;
  _Float16* A2h = (_Float16*)(opart + (size_t)SPLIT * NN * FO);

  k_s1         <<<NN / 16,           256, 0, stream>>>(x, W1, S1);
  k_pass1_fused<<<(NN / BM) * SPLIT, 256, 0, stream>>>(adj, S1, pi1, pi2, hpart, A2h);
  k_mid        <<<NN / 4,            256, 0, stream>>>(hpart, b1, W2, HW);
  k_pass2_half <<<(NN / BM) * SPLIT, 256, 0, stream>>>(A2h, HW, opart);
  k_fin        <<<(NN * FO) / 256,   256, 0, stream>>>(opart, b2, out);
}

// Round 8
// 349.162 us; speedup vs baseline: 1.0173x; 1.0173x over previous
//
#include <hip/hip_runtime.h>
#include <stdint.h>

#define NN 8192
#define FIN 128
#define FH 64
#define FO 16
#define BM 64
#define BN 64
#define SPLIT1 4
#define NRANGE1 (NN / SPLIT1)   // 2048
#define NCHUNK1 (NRANGE1 / BN)  // 32
#define SPLIT2 16
#define NRANGE2 (NN / SPLIT2)   // 512

typedef float    f32x4 __attribute__((ext_vector_type(4)));
typedef _Float16 f16x4 __attribute__((ext_vector_type(4)));
typedef _Float16 f16x8 __attribute__((ext_vector_type(8)));
typedef _Float16 h2    __attribute__((ext_vector_type(2)));

union U8 { f16x8 v; h2 p[4]; };

static __device__ __forceinline__ void fma4(float4& acc, float a, const float4 s) {
  acc.x = fmaf(a, s.x, acc.x);
  acc.y = fmaf(a, s.y, acc.y);
  acc.z = fmaf(a, s.z, acc.z);
  acc.w = fmaf(a, s.w, acc.w);
}

static __device__ __forceinline__ float dot2(h2 a, h2 b, float c) {
#if defined(__has_builtin)
#if __has_builtin(__builtin_amdgcn_fdot2)
  return __builtin_amdgcn_fdot2(a, b, c, false);
#else
  return c + (float)a.x * (float)b.x + (float)a.y * (float)b.y;
#endif
#else
  return c + (float)a.x * (float)b.x + (float)a.y * (float)b.y;
#endif
}

// ---------------- S1 = x @ W1  (8192x128 @ 128x64) ----------------
__global__ __launch_bounds__(256) void k_s1(const float* __restrict__ x,
                                            const float* __restrict__ W1,
                                            float* __restrict__ S1) {
  __shared__ float W1l[FIN * FH];
  __shared__ float xl[16][FIN + 4];
  const int t = threadIdx.x;
  const int n0 = blockIdx.x * 16;
  for (int i = t; i < FIN * FH / 4; i += 256)
    ((float4*)W1l)[i] = ((const float4*)W1)[i];
  for (int i = t; i < 16 * FIN; i += 256) {
    int r = i >> 7, c = i & (FIN - 1);
    xl[r][c] = x[(size_t)(n0 + r) * FIN + c];
  }
  __syncthreads();
  const int m = t >> 4;
  const int j0 = (t & 15) << 2;
  float4 acc = {0.f, 0.f, 0.f, 0.f};
#pragma unroll 8
  for (int k = 0; k < FIN; ++k) {
    float xv = xl[m][k];
    float4 w = *(const float4*)&W1l[k * FH + j0];
    fma4(acc, xv, w);
  }
  *(float4*)&S1[(size_t)(n0 + m) * FH + j0] = acc;
}

// ===== pass 1 (FUSED, R5-proven): hpart[sp] = (softmax(pi1)·adj)@S1 ; emit A2h = fp16(pi2·adj) =====
__global__ __launch_bounds__(256) void k_pass1_fused(const float* __restrict__ adj,
                                                     const float* __restrict__ S1,
                                                     const float* __restrict__ pi1,
                                                     const float* __restrict__ pi2,
                                                     float* __restrict__ hpart,
                                                     _Float16* __restrict__ A2h) {
  __shared__ float Alds[BN][BM];   // [n][m ^ (n&60)]  16 KB
  __shared__ float S1l[BN][FH];    // 16 KB
  const int t = threadIdx.x;
  const int mb = blockIdx.x >> 2;
  const int sp = blockIdx.x & 3;

  float p0 = pi1[0], p1 = pi1[1], p2 = pi1[2], p3 = pi1[3];
  float mx = fmaxf(fmaxf(p0, p1), fmaxf(p2, p3));
  float e0 = expf(p0 - mx), e1 = expf(p1 - mx), e2 = expf(p2 - mx), e3 = expf(p3 - mx);
  float inv = 1.0f / (e0 + e1 + e2 + e3);
  const float w0 = e0 * inv, w1 = e1 * inv, w2 = e2 * inv, w3 = e3 * inv;
  const float v0 = pi2[0], v1 = pi2[1], v2 = pi2[2], v3 = pi2[3];   // raw pi2

  const size_t NN2 = (size_t)NN * NN;
  const size_t row0 = (size_t)mb * BM;
  const int nbase = sp * NRANGE1;

  const int n4 = t & 15;
  const int ms = t >> 4;
  const int m0 = (t & 15) << 2;
  const int j0 = (t >> 4) << 2;

  f32x4 pf[4][4];
  f32x4 pfS[4];

  float4 acc0 = {0,0,0,0}, acc1 = {0,0,0,0}, acc2 = {0,0,0,0}, acc3 = {0,0,0,0};

  auto ISSUE = [&](int c) {
    const int n0 = nbase + c * BN;
#pragma unroll
    for (int p = 0; p < 4; ++p) {
      const float* g = adj + (row0 + (size_t)(ms + (p << 4))) * NN + (size_t)(n0 + (n4 << 2));
      pf[p][0] = __builtin_nontemporal_load((const f32x4*)g);
      pf[p][1] = __builtin_nontemporal_load((const f32x4*)(g + NN2));
      pf[p][2] = __builtin_nontemporal_load((const f32x4*)(g + 2 * NN2));
      pf[p][3] = __builtin_nontemporal_load((const f32x4*)(g + 3 * NN2));
    }
    const f32x4* src = (const f32x4*)(S1 + (size_t)n0 * FH);
#pragma unroll
    for (int i = 0; i < 4; ++i) pfS[i] = src[t + 256 * i];
  };

  auto STAGE = [&](int c) {
    const int n0 = nbase + c * BN;
#pragma unroll
    for (int p = 0; p < 4; ++p) {
      const int ml = ms + (p << 4);
      const int mc = ml ^ (n4 << 2);
      f32x4 a0 = pf[p][0], a1 = pf[p][1], a2 = pf[p][2], a3 = pf[p][3];
      Alds[(n4 << 2) + 0][mc] = fmaf(w0, a0.x, fmaf(w1, a1.x, fmaf(w2, a2.x, w3 * a3.x)));
      Alds[(n4 << 2) + 1][mc] = fmaf(w0, a0.y, fmaf(w1, a1.y, fmaf(w2, a2.y, w3 * a3.y)));
      Alds[(n4 << 2) + 2][mc] = fmaf(w0, a0.z, fmaf(w1, a1.z, fmaf(w2, a2.z, w3 * a3.z)));
      Alds[(n4 << 2) + 3][mc] = fmaf(w0, a0.w, fmaf(w1, a1.w, fmaf(w2, a2.w, w3 * a3.w)));
      f16x4 h4;
      h4.x = (_Float16)fmaf(v0, a0.x, fmaf(v1, a1.x, fmaf(v2, a2.x, v3 * a3.x)));
      h4.y = (_Float16)fmaf(v0, a0.y, fmaf(v1, a1.y, fmaf(v2, a2.y, v3 * a3.y)));
      h4.z = (_Float16)fmaf(v0, a0.z, fmaf(v1, a1.z, fmaf(v2, a2.z, v3 * a3.z)));
      h4.w = (_Float16)fmaf(v0, a0.w, fmaf(v1, a1.w, fmaf(v2, a2.w, v3 * a3.w)));
      *(f16x4*)(A2h + (row0 + (size_t)ml) * NN + (size_t)(n0 + (n4 << 2))) = h4;
    }
    f32x4* dst = (f32x4*)&S1l[0][0];
#pragma unroll
    for (int i = 0; i < 4; ++i) dst[t + 256 * i] = pfS[i];
  };

  ISSUE(0);
  for (int c = 0; c < NCHUNK1; ++c) {
    __syncthreads();
    STAGE(c);
    if (c + 1 < NCHUNK1) ISSUE(c + 1);
    asm volatile("s_waitcnt lgkmcnt(0)" ::: "memory");
    __builtin_amdgcn_s_barrier();
#pragma unroll 4
    for (int n = 0; n < BN; ++n) {
      const float4 a = *(const float4*)&Alds[n][m0 ^ (n & 60)];
      const float4 s = *(const float4*)&S1l[n][j0];
      fma4(acc0, a.x, s);
      fma4(acc1, a.y, s);
      fma4(acc2, a.z, s);
      fma4(acc3, a.w, s);
    }
  }
  float* hp = hpart + (size_t)sp * NN * FH;
  const size_t rbase = (row0 + m0) * FH + j0;
  *(float4*)&hp[rbase]          = acc0;
  *(float4*)&hp[rbase + FH]     = acc1;
  *(float4*)&hp[rbase + 2 * FH] = acc2;
  *(float4*)&hp[rbase + 3 * FH] = acc3;
}

// ---------------- exact JAX threefry2x32 dropout (partitionable path), key=(0,42) ----------
__device__ __forceinline__ float dropout_scale(uint32_t e) {
  uint32_t x0 = 0u;
  uint32_t x1 = e;
  const uint32_t ks1 = 42u;
  const uint32_t ks2 = 0x1BD11BF0u;
  x1 += ks1;
#define TFR(d) { x0 += x1; x1 = (x1 << d) | (x1 >> (32 - d)); x1 ^= x0; }
  TFR(13) TFR(15) TFR(26) TFR(6)   x0 += ks1; x1 += ks2 + 1u;
  TFR(17) TFR(29) TFR(16) TFR(24)  x0 += ks2; x1 += 0u  + 2u;
  TFR(13) TFR(15) TFR(26) TFR(6)   x0 += 0u;  x1 += ks1 + 3u;
  TFR(17) TFR(29) TFR(16) TFR(24)  x0 += ks1; x1 += ks2 + 4u;
  TFR(13) TFR(15) TFR(26) TFR(6)   x0 += ks2; x1 += 0u  + 5u;
#undef TFR
  uint32_t bits = x0 ^ x1;
  float u = __uint_as_float((bits >> 9) | 0x3f800000u) - 1.0f;
  return (u < 0.7f) ? (1.0f / 0.7f) : 0.0f;
}

// ---------------- mid: h = dropout(relu(sum_sp hpart + b1)); HWT(fp16) = (h @ W2)^T ----------
__global__ __launch_bounds__(256) void k_mid(const float* __restrict__ hpart,
                                             const float* __restrict__ b1,
                                             const float* __restrict__ W2,
                                             _Float16* __restrict__ HWT) {
  __shared__ float hl[4][FH];
  __shared__ float W2l[FH * FO];
  const int t = threadIdx.x;
  const int n0 = blockIdx.x << 2;
  for (int i = t; i < FH * FO; i += 256) W2l[i] = W2[i];
  const int j = t & 63, r = t >> 6;
  const uint32_t idx = (uint32_t)(n0 + r) * FH + j;
  const size_t NF = (size_t)NN * FH;
  float pre = b1[j];
#pragma unroll
  for (int s = 0; s < SPLIT1; ++s) pre += hpart[idx + (size_t)s * NF];
  float v = fmaxf(pre, 0.0f) * dropout_scale(idx);
  hl[r][j] = v;
  __syncthreads();
  if (t < 64) {
    const int rr = t >> 4, f = t & 15;
    float s = 0.f;
#pragma unroll 8
    for (int jj = 0; jj < FH; ++jj)
      s = fmaf(hl[rr][jj], W2l[jj * FO + f], s);
    HWT[(size_t)f * NN + (n0 + rr)] = (_Float16)s;
  }
}

// ---------------- init: out = b2 (atomic accumulation target) ----------------
__global__ __launch_bounds__(256) void k_init(const float* __restrict__ b2,
                                              float* __restrict__ out) {
  const int e = blockIdx.x * 256 + threadIdx.x;
  out[e] = b2[e & 15];
}

// ===== pass 2 (dot2): out += A2h(fp16, regs) @ HWT(fp16, LDS) — 64-thr blocks, no inner barriers =====
__global__ __launch_bounds__(64) void k_pass2_dot(const _Float16* __restrict__ A2h,
                                                  const _Float16* __restrict__ HWT,
                                                  float* __restrict__ out) {
  // Htl interleaved [64 n-octs][16 f][8 halves]: byte = o*256 + f*16 (2-way spread across fgrp = free)
  __shared__ f16x8 Htl[64 * 16];   // 16 KB
  const int t = threadIdx.x;       // 0..63
  const int mb = blockIdx.x >> 4;  // 0..127
  const int sp = blockIdx.x & 15;  // 0..15
  const size_t row0 = (size_t)mb * BM;
  const int nbase = sp * NRANGE2;

  // stage HWT slice: f16x8 per (i=f, t=oct)
#pragma unroll
  for (int i = 0; i < FO; ++i)
    Htl[t * FO + i] = *(const f16x8*)(HWT + (size_t)i * NN + nbase + t * 8);
  __syncthreads();

  const int fgrp = t & 3;          // f0 = fgrp*4
  const int mgrp = t >> 2;         // rows m0 = mgrp*4
  const size_t rbase = (row0 + (size_t)mgrp * 4) * NN + nbase;

  float acc[4][4];
#pragma unroll
  for (int j = 0; j < 4; ++j)
#pragma unroll
    for (int i = 0; i < 4; ++i) acc[j][i] = 0.f;

  f16x8 aA[4], aB[4];
#pragma unroll
  for (int j = 0; j < 4; ++j)
    aA[j] = *(const f16x8*)(A2h + rbase + (size_t)j * NN);   // o = 0

  auto LOADB = [&](int o) {
#pragma unroll
    for (int j = 0; j < 4; ++j)
      aB[j] = *(const f16x8*)(A2h + rbase + (size_t)j * NN + o * 8);
  };
  auto LOADA = [&](int o) {
#pragma unroll
    for (int j = 0; j < 4; ++j)
      aA[j] = *(const f16x8*)(A2h + rbase + (size_t)j * NN + o * 8);
  };

  auto COMPUTE = [&](const f16x8* buf, int o) {
    U8 h0, h1, h2v, h3;
    h0.v  = Htl[o * FO + fgrp * 4 + 0];
    h1.v  = Htl[o * FO + fgrp * 4 + 1];
    h2v.v = Htl[o * FO + fgrp * 4 + 2];
    h3.v  = Htl[o * FO + fgrp * 4 + 3];
#pragma unroll
    for (int j = 0; j < 4; ++j) {
      U8 a;
      a.v = buf[j];
#pragma unroll
      for (int q = 0; q < 4; ++q) {
        h2 pa = a.p[q];
        acc[j][0] = dot2(pa, h0.p[q],  acc[j][0]);
        acc[j][1] = dot2(pa, h1.p[q],  acc[j][1]);
        acc[j][2] = dot2(pa, h2v.p[q], acc[j][2]);
        acc[j][3] = dot2(pa, h3.p[q],  acc[j][3]);
      }
    }
  };

  for (int o = 0; o < 64; o += 2) {
    LOADB(o + 1);
    COMPUTE(aA, o);
    if (o + 2 < 64) LOADA(o + 2);
    COMPUTE(aB, o + 1);
  }

#pragma unroll
  for (int j = 0; j < 4; ++j)
#pragma unroll
    for (int i = 0; i < 4; ++i)
      atomicAdd(&out[(row0 + (size_t)mgrp * 4 + j) * FO + fgrp * 4 + i], acc[j][i]);
}

extern "C" void kernel_launch(void* const* d_in, const int* in_sizes, int n_in,
                              void* d_out, int out_size, void* d_ws, size_t ws_size,
                              hipStream_t stream) {
  const float* adj = (const float*)d_in[0];
  const float* x   = (const float*)d_in[1];
  const float* W1  = (const float*)d_in[2];
  const float* b1  = (const float*)d_in[3];
  const float* W2  = (const float*)d_in[4];
  const float* b2  = (const float*)d_in[5];
  const float* pi1 = (const float*)d_in[6];
  const float* pi2 = (const float*)d_in[7];
  float* out = (float*)d_out;
  float* ws  = (float*)d_ws;

  // ws layout: S1 f32[NN*FH] | hpart f32[4*NN*FH] | A2h fp16[NN*NN] | HWT fp16[FO*NN]  (~138.3 MB)
  float* S1    = ws;
  float* hpart = S1 + (size_t)NN * FH;
  _Float16* A2h = (_Float16*)(hpart + (size_t)SPLIT1 * NN * FH);
  _Float16* HWT = A2h + (size_t)NN * NN;

  k_s1         <<<NN / 16,            256, 0, stream>>>(x, W1, S1);
  k_pass1_fused<<<(NN / BM) * SPLIT1, 256, 0, stream>>>(adj, S1, pi1, pi2, hpart, A2h);
  k_mid        <<<NN / 4,             256, 0, stream>>>(hpart, b1, W2, HWT);
  k_init       <<<(NN * FO) / 256,    256, 0, stream>>>(b2, out);
  k_pass2_dot  <<<(NN / BM) * SPLIT2,  64, 0, stream>>>(A2h, HWT, out);
}

// Round 9
// 337.016 us; speedup vs baseline: 1.0540x; 1.0360x over previous
//
#include <hip/hip_runtime.h>
#include <stdint.h>

#define NN 8192
#define FIN 128
#define FH 64
#define FO 16
#define BM 64
#define BN 64
#define SPLIT1 4
#define NRANGE1 (NN / SPLIT1)   // 2048
#define NCHUNK1 (NRANGE1 / BN)  // 32
#define SPLIT2 16
#define NRANGE2 (NN / SPLIT2)   // 512

typedef float    f32x4 __attribute__((ext_vector_type(4)));
typedef _Float16 f16x4 __attribute__((ext_vector_type(4)));
typedef _Float16 f16x8 __attribute__((ext_vector_type(8)));
typedef _Float16 h2    __attribute__((ext_vector_type(2)));

union U8 { f16x8 v; h2 p[4]; };

static __device__ __forceinline__ void fma4(float4& acc, float a, const float4 s) {
  acc.x = fmaf(a, s.x, acc.x);
  acc.y = fmaf(a, s.y, acc.y);
  acc.z = fmaf(a, s.z, acc.z);
  acc.w = fmaf(a, s.w, acc.w);
}

static __device__ __forceinline__ float dot2(h2 a, h2 b, float c) {
#if defined(__has_builtin)
#if __has_builtin(__builtin_amdgcn_fdot2)
  return __builtin_amdgcn_fdot2(a, b, c, false);
#else
  return c + (float)a.x * (float)b.x + (float)a.y * (float)b.y;
#endif
#else
  return c + (float)a.x * (float)b.x + (float)a.y * (float)b.y;
#endif
}

// ---------------- S1p = pack_fp16_pairs(x @ W1)  -> [np][j][2] layout ----------------
__global__ __launch_bounds__(256) void k_s1(const float* __restrict__ x,
                                            const float* __restrict__ W1,
                                            _Float16* __restrict__ S1p) {
  __shared__ float W1l[FIN * FH];
  __shared__ float xl[16][FIN + 4];
  __shared__ float hl[16][FH];
  const int t = threadIdx.x;
  const int n0 = blockIdx.x * 16;
  for (int i = t; i < FIN * FH / 4; i += 256)
    ((float4*)W1l)[i] = ((const float4*)W1)[i];
  for (int i = t; i < 16 * FIN; i += 256) {
    int r = i >> 7, c = i & (FIN - 1);
    xl[r][c] = x[(size_t)(n0 + r) * FIN + c];
  }
  __syncthreads();
  const int m = t >> 4;
  const int j0 = (t & 15) << 2;
  float4 acc = {0.f, 0.f, 0.f, 0.f};
#pragma unroll 8
  for (int k = 0; k < FIN; ++k) {
    float xv = xl[m][k];
    float4 w = *(const float4*)&W1l[k * FH + j0];
    fma4(acc, xv, w);
  }
  *(float4*)&hl[m][j0] = acc;
  __syncthreads();
  // pack n-pairs: S1p[npg][j][2]
  const int j = t & 63;
  const int g = t >> 6;             // 0..3
#pragma unroll
  for (int e = 0; e < 2; ++e) {
    const int np = g * 2 + e;       // 0..7 local
    h2 v;
    v.x = (_Float16)hl[np * 2 + 0][j];
    v.y = (_Float16)hl[np * 2 + 1][j];
    *(h2*)&S1p[(((size_t)(n0 >> 1) + np) * FH + j) * 2] = v;
  }
}

// ===== pass 1 (FUSED, fp16-LDS dot2): hpart[sp] = (softmax(pi1)·adj)@S1 ; emit A2h = fp16(pi2·adj) =====
__global__ __launch_bounds__(256) void k_pass1_fused(const float* __restrict__ adj,
                                                     const _Float16* __restrict__ S1p,
                                                     const float* __restrict__ pi1,
                                                     const float* __restrict__ pi2,
                                                     float* __restrict__ hpart,
                                                     _Float16* __restrict__ A2h) {
  __shared__ h2 Alds[BN / 2][BM];          // [np][m ^ ((np&7)<<2)]  8 KB
  __shared__ _Float16 S1l[BN / 2][FH][2];  // [np][j][pair]          8 KB
  const int t = threadIdx.x;
  const int mb = blockIdx.x >> 2;
  const int sp = blockIdx.x & 3;

  float p0 = pi1[0], p1 = pi1[1], p2 = pi1[2], p3 = pi1[3];
  float mx = fmaxf(fmaxf(p0, p1), fmaxf(p2, p3));
  float e0 = expf(p0 - mx), e1 = expf(p1 - mx), e2 = expf(p2 - mx), e3 = expf(p3 - mx);
  float inv = 1.0f / (e0 + e1 + e2 + e3);
  const float w0 = e0 * inv, w1 = e1 * inv, w2 = e2 * inv, w3 = e3 * inv;
  const float v0 = pi2[0], v1 = pi2[1], v2 = pi2[2], v3 = pi2[3];   // raw pi2

  const size_t NN2 = (size_t)NN * NN;
  const size_t row0 = (size_t)mb * BM;
  const int nbase = sp * NRANGE1;

  const int n4 = t & 15;           // n-quad (staging)
  const int ms = t >> 4;           // row slot (staging), row = ms + 16*p
  const int m0 = (t & 15) << 2;    // compute: 4 rows
  const int j0 = (t >> 4) << 2;    // compute: 4 cols

  f32x4 pf[4][4];
  f16x8 pfS[2];

  float4 acc0 = {0,0,0,0}, acc1 = {0,0,0,0}, acc2 = {0,0,0,0}, acc3 = {0,0,0,0};

  auto ISSUE = [&](int c) {
    const int n0 = nbase + c * BN;
#pragma unroll
    for (int p = 0; p < 4; ++p) {
      const float* g = adj + (row0 + (size_t)(ms + (p << 4))) * NN + (size_t)(n0 + (n4 << 2));
      pf[p][0] = __builtin_nontemporal_load((const f32x4*)g);
      pf[p][1] = __builtin_nontemporal_load((const f32x4*)(g + NN2));
      pf[p][2] = __builtin_nontemporal_load((const f32x4*)(g + 2 * NN2));
      pf[p][3] = __builtin_nontemporal_load((const f32x4*)(g + 3 * NN2));
    }
    const f16x8* src = (const f16x8*)(S1p + (size_t)(n0 >> 1) * FH * 2);
    pfS[0] = src[t];
    pfS[1] = src[t + 256];
  };

  auto STAGE = [&](int c) {
    const int n0 = nbase + c * BN;
#pragma unroll
    for (int p = 0; p < 4; ++p) {
      const int ml = ms + (p << 4);
      f32x4 a0 = pf[p][0], a1 = pf[p][1], a2 = pf[p][2], a3 = pf[p][3];
      float c0 = fmaf(w0, a0.x, fmaf(w1, a1.x, fmaf(w2, a2.x, w3 * a3.x)));
      float c1 = fmaf(w0, a0.y, fmaf(w1, a1.y, fmaf(w2, a2.y, w3 * a3.y)));
      float c2 = fmaf(w0, a0.z, fmaf(w1, a1.z, fmaf(w2, a2.z, w3 * a3.z)));
      float c3 = fmaf(w0, a0.w, fmaf(w1, a1.w, fmaf(w2, a2.w, w3 * a3.w)));
      const int np0 = n4 * 2, np1 = np0 + 1;
      h2 u01; u01.x = (_Float16)c0; u01.y = (_Float16)c1;
      h2 u23; u23.x = (_Float16)c2; u23.y = (_Float16)c3;
      Alds[np0][ml ^ ((np0 & 7) << 2)] = u01;
      Alds[np1][ml ^ ((np1 & 7) << 2)] = u23;
      // A2 fp16 emit (reuses adj regs)
      f16x4 h4;
      h4.x = (_Float16)fmaf(v0, a0.x, fmaf(v1, a1.x, fmaf(v2, a2.x, v3 * a3.x)));
      h4.y = (_Float16)fmaf(v0, a0.y, fmaf(v1, a1.y, fmaf(v2, a2.y, v3 * a3.y)));
      h4.z = (_Float16)fmaf(v0, a0.z, fmaf(v1, a1.z, fmaf(v2, a2.z, v3 * a3.z)));
      h4.w = (_Float16)fmaf(v0, a0.w, fmaf(v1, a1.w, fmaf(v2, a2.w, v3 * a3.w)));
      *(f16x4*)(A2h + (row0 + (size_t)ml) * NN + (size_t)(n0 + (n4 << 2))) = h4;
    }
    f16x8* dst = (f16x8*)&S1l[0][0][0];
    dst[t]       = pfS[0];
    dst[t + 256] = pfS[1];
  };

  ISSUE(0);
  for (int c = 0; c < NCHUNK1; ++c) {
    __syncthreads();                 // drains vmcnt(0): prefetched loads completed during compute
    STAGE(c);
    if (c + 1 < NCHUNK1) ISSUE(c + 1);
    asm volatile("s_waitcnt lgkmcnt(0)" ::: "memory");
    __builtin_amdgcn_s_barrier();
#pragma unroll 4
    for (int np = 0; np < BN / 2; ++np) {
      const int s = (np & 7) << 2;
      U8 a;  a.v  = *(const f16x8*)&Alds[np][m0 ^ s];         // rows m0..m0+3, n-pair np
      U8 sv; sv.v = *(const f16x8*)&S1l[np][j0][0];           // cols j0..j0+3, n-pair np
      acc0.x = dot2(a.p[0], sv.p[0], acc0.x);
      acc0.y = dot2(a.p[0], sv.p[1], acc0.y);
      acc0.z = dot2(a.p[0], sv.p[2], acc0.z);
      acc0.w = dot2(a.p[0], sv.p[3], acc0.w);
      acc1.x = dot2(a.p[1], sv.p[0], acc1.x);
      acc1.y = dot2(a.p[1], sv.p[1], acc1.y);
      acc1.z = dot2(a.p[1], sv.p[2], acc1.z);
      acc1.w = dot2(a.p[1], sv.p[3], acc1.w);
      acc2.x = dot2(a.p[2], sv.p[0], acc2.x);
      acc2.y = dot2(a.p[2], sv.p[1], acc2.y);
      acc2.z = dot2(a.p[2], sv.p[2], acc2.z);
      acc2.w = dot2(a.p[2], sv.p[3], acc2.w);
      acc3.x = dot2(a.p[3], sv.p[0], acc3.x);
      acc3.y = dot2(a.p[3], sv.p[1], acc3.y);
      acc3.z = dot2(a.p[3], sv.p[2], acc3.z);
      acc3.w = dot2(a.p[3], sv.p[3], acc3.w);
    }
  }
  float* hp = hpart + (size_t)sp * NN * FH;
  const size_t rbase = (row0 + m0) * FH + j0;
  *(float4*)&hp[rbase]          = acc0;
  *(float4*)&hp[rbase + FH]     = acc1;
  *(float4*)&hp[rbase + 2 * FH] = acc2;
  *(float4*)&hp[rbase + 3 * FH] = acc3;
}

// ---------------- exact JAX threefry2x32 dropout (partitionable path), key=(0,42) ----------
__device__ __forceinline__ float dropout_scale(uint32_t e) {
  uint32_t x0 = 0u;
  uint32_t x1 = e;
  const uint32_t ks1 = 42u;
  const uint32_t ks2 = 0x1BD11BF0u;
  x1 += ks1;
#define TFR(d) { x0 += x1; x1 = (x1 << d) | (x1 >> (32 - d)); x1 ^= x0; }
  TFR(13) TFR(15) TFR(26) TFR(6)   x0 += ks1; x1 += ks2 + 1u;
  TFR(17) TFR(29) TFR(16) TFR(24)  x0 += ks2; x1 += 0u  + 2u;
  TFR(13) TFR(15) TFR(26) TFR(6)   x0 += 0u;  x1 += ks1 + 3u;
  TFR(17) TFR(29) TFR(16) TFR(24)  x0 += ks1; x1 += ks2 + 4u;
  TFR(13) TFR(15) TFR(26) TFR(6)   x0 += ks2; x1 += 0u  + 5u;
#undef TFR
  uint32_t bits = x0 ^ x1;
  float u = __uint_as_float((bits >> 9) | 0x3f800000u) - 1.0f;
  return (u < 0.7f) ? (1.0f / 0.7f) : 0.0f;
}

// ---------------- mid: h = dropout(relu(sum_sp hpart + b1)); HWT(fp16) = (h @ W2)^T ----------
__global__ __launch_bounds__(256) void k_mid(const float* __restrict__ hpart,
                                             const float* __restrict__ b1,
                                             const float* __restrict__ W2,
                                             _Float16* __restrict__ HWT) {
  __shared__ float hl[4][FH];
  __shared__ float W2l[FH * FO];
  const int t = threadIdx.x;
  const int n0 = blockIdx.x << 2;
  for (int i = t; i < FH * FO; i += 256) W2l[i] = W2[i];
  const int j = t & 63, r = t >> 6;
  const uint32_t idx = (uint32_t)(n0 + r) * FH + j;
  const size_t NF = (size_t)NN * FH;
  float pre = b1[j];
#pragma unroll
  for (int s = 0; s < SPLIT1; ++s) pre += hpart[idx + (size_t)s * NF];
  float v = fmaxf(pre, 0.0f) * dropout_scale(idx);
  hl[r][j] = v;
  __syncthreads();
  if (t < 64) {
    const int rr = t >> 4, f = t & 15;
    float s = 0.f;
#pragma unroll 8
    for (int jj = 0; jj < FH; ++jj)
      s = fmaf(hl[rr][jj], W2l[jj * FO + f], s);
    HWT[(size_t)f * NN + (n0 + rr)] = (_Float16)s;
  }
}

// ---------------- init: out = b2 (atomic accumulation target) ----------------
__global__ __launch_bounds__(256) void k_init(const float* __restrict__ b2,
                                              float* __restrict__ out) {
  const int e = blockIdx.x * 256 + threadIdx.x;
  out[e] = b2[e & 15];
}

// ===== pass 2 (dot2): out += A2h(fp16, regs) @ HWT(fp16, LDS) — 64-thr blocks, no inner barriers =====
__global__ __launch_bounds__(64) void k_pass2_dot(const _Float16* __restrict__ A2h,
                                                  const _Float16* __restrict__ HWT,
                                                  float* __restrict__ out) {
  __shared__ f16x8 Htl[64 * 16];   // 16 KB
  const int t = threadIdx.x;       // 0..63
  const int mb = blockIdx.x >> 4;  // 0..127
  const int sp = blockIdx.x & 15;  // 0..15
  const size_t row0 = (size_t)mb * BM;
  const int nbase = sp * NRANGE2;

#pragma unroll
  for (int i = 0; i < FO; ++i)
    Htl[t * FO + i] = *(const f16x8*)(HWT + (size_t)i * NN + nbase + t * 8);
  __syncthreads();

  const int fgrp = t & 3;
  const int mgrp = t >> 2;
  const size_t rbase = (row0 + (size_t)mgrp * 4) * NN + nbase;

  float acc[4][4];
#pragma unroll
  for (int j = 0; j < 4; ++j)
#pragma unroll
    for (int i = 0; i < 4; ++i) acc[j][i] = 0.f;

  f16x8 aA[4], aB[4];
#pragma unroll
  for (int j = 0; j < 4; ++j)
    aA[j] = *(const f16x8*)(A2h + rbase + (size_t)j * NN);

  auto LOADB = [&](int o) {
#pragma unroll
    for (int j = 0; j < 4; ++j)
      aB[j] = *(const f16x8*)(A2h + rbase + (size_t)j * NN + o * 8);
  };
  auto LOADA = [&](int o) {
#pragma unroll
    for (int j = 0; j < 4; ++j)
      aA[j] = *(const f16x8*)(A2h + rbase + (size_t)j * NN + o * 8);
  };

  auto COMPUTE = [&](const f16x8* buf, int o) {
    U8 h0, h1, h2v, h3;
    h0.v  = Htl[o * FO + fgrp * 4 + 0];
    h1.v  = Htl[o * FO + fgrp * 4 + 1];
    h2v.v = Htl[o * FO + fgrp * 4 + 2];
    h3.v  = Htl[o * FO + fgrp * 4 + 3];
#pragma unroll
    for (int j = 0; j < 4; ++j) {
      U8 a;
      a.v = buf[j];
#pragma unroll
      for (int q = 0; q < 4; ++q) {
        h2 pa = a.p[q];
        acc[j][0] = dot2(pa, h0.p[q],  acc[j][0]);
        acc[j][1] = dot2(pa, h1.p[q],  acc[j][1]);
        acc[j][2] = dot2(pa, h2v.p[q], acc[j][2]);
        acc[j][3] = dot2(pa, h3.p[q],  acc[j][3]);
      }
    }
  };

  for (int o = 0; o < 64; o += 2) {
    LOADB(o + 1);
    COMPUTE(aA, o);
    if (o + 2 < 64) LOADA(o + 2);
    COMPUTE(aB, o + 1);
  }

#pragma unroll
  for (int j = 0; j < 4; ++j)
#pragma unroll
    for (int i = 0; i < 4; ++i)
      atomicAdd(&out[(row0 + (size_t)mgrp * 4 + j) * FO + fgrp * 4 + i], acc[j][i]);
}

extern "C" void kernel_launch(void* const* d_in, const int* in_sizes, int n_in,
                              void* d_out, int out_size, void* d_ws, size_t ws_size,
                              hipStream_t stream) {
  const float* adj = (const float*)d_in[0];
  const float* x   = (const float*)d_in[1];
  const float* W1  = (const float*)d_in[2];
  const float* b1  = (const float*)d_in[3];
  const float* W2  = (const float*)d_in[4];
  const float* b2  = (const float*)d_in[5];
  const float* pi1 = (const float*)d_in[6];
  const float* pi2 = (const float*)d_in[7];
  float* out = (float*)d_out;
  float* ws  = (float*)d_ws;

  // ws layout: hpart f32[4*NN*FH] | S1p fp16[NN*FH] | A2h fp16[NN*NN] | HWT fp16[FO*NN]  (~137.5 MB)
  float* hpart  = ws;
  _Float16* S1p = (_Float16*)(hpart + (size_t)SPLIT1 * NN * FH);
  _Float16* A2h = S1p + (size_t)NN * FH;
  _Float16* HWT = A2h + (size_t)NN * NN;

  k_s1         <<<NN / 16,            256, 0, stream>>>(x, W1, S1p);
  k_pass1_fused<<<(NN / BM) * SPLIT1, 256, 0, stream>>>(adj, S1p, pi1, pi2, hpart, A2h);
  k_mid        <<<NN / 4,             256, 0, stream>>>(hpart, b1, W2, HWT);
  k_init       <<<(NN * FO) / 256,    256, 0, stream>>>(b2, out);
  k_pass2_dot  <<<(NN / BM) * SPLIT2,  64, 0, stream>>>(A2h, HWT, out);
}